// Round 2
// baseline (1745.112 us; speedup 1.0000x reference)
//
#include <hip/hip_runtime.h>
#include <hip/hip_bf16.h>
#include <stdint.h>

#define N_CLAIM    100000
#define N_ENTITY   200000
#define N_EVIDENCE 150000
#define NEDGE      2000000
#define F          64
#define NT         550000      // concat dst counts: claim(t0)+claim(t1)+entity(t2)+evidence(t3)
#define NB_SCAN    538         // ceil(NT/1024)
#define BATCH      50000

static __device__ __forceinline__ float b2f(unsigned short u){
  return __uint_as_float(((unsigned int)u) << 16);
}
static __device__ __forceinline__ unsigned short f2b(float f){
  unsigned int x = __float_as_uint(f);
  x += 0x7fffu + ((x >> 16) & 1u);   // RNE
  return (unsigned short)(x >> 16);
}

// ---------------- fp32 -> bf16 cast ----------------
__global__ void k_cast(const float* __restrict__ in, unsigned short* __restrict__ out, int n4){
  int i = blockIdx.x * blockDim.x + threadIdx.x;
  if (i >= n4) return;
  float4 v = ((const float4*)in)[i];
  ushort4 o;
  o.x = f2b(v.x); o.y = f2b(v.y); o.z = f2b(v.z); o.w = f2b(v.w);
  ((ushort4*)out)[i] = o;
}

// ---------------- CSR build ----------------
__global__ void k_hist(const int* __restrict__ ei, int* __restrict__ cnt){
  long long i = (long long)blockIdx.x * blockDim.x + threadIdx.x;
  if (i >= 4LL * NEDGE) return;
  int t = (int)(i / NEDGE);
  int e = (int)(i - (long long)t * NEDGE);
  const int toff[4] = {0, N_CLAIM, 2*N_CLAIM, 2*N_CLAIM + N_ENTITY};
  int dst = ei[(long long)t * 2 * NEDGE + NEDGE + e];
  atomicAdd(cnt + toff[t] + dst, 1);
}

__global__ void k_blocksum(const int* __restrict__ cnt, int* __restrict__ part){
  int b = blockIdx.x, tid = threadIdx.x;
  int base = b * 1024;
  int v = 0;
  #pragma unroll
  for (int j = 0; j < 4; j++){
    int idx = base + tid + j * 256;
    if (idx < NT) v += cnt[idx];
  }
  #pragma unroll
  for (int off = 1; off < 64; off <<= 1) v += __shfl_xor(v, off, 64);
  __shared__ int s[4];
  if ((tid & 63) == 0) s[tid >> 6] = v;
  __syncthreads();
  if (tid == 0) part[b] = s[0] + s[1] + s[2] + s[3];
}

__global__ void k_scanpart(int* __restrict__ part, int* __restrict__ R){
  __shared__ int s[1024];
  int tid = threadIdx.x;
  int v = (tid < NB_SCAN) ? part[tid] : 0;
  s[tid] = v;
  __syncthreads();
  for (int off = 1; off < 1024; off <<= 1){
    int t = (tid >= off) ? s[tid - off] : 0;
    __syncthreads();
    s[tid] += t;
    __syncthreads();
  }
  if (tid < NB_SCAN) part[tid] = s[tid] - v;   // exclusive
  if (tid == 1023) R[NT] = s[1023];            // total (= 4*NEDGE)
}

__global__ void k_scanfinal(const int* __restrict__ cnt, const int* __restrict__ part,
                            int* __restrict__ R, int* __restrict__ cur){
  __shared__ int s[1024];
  int b = blockIdx.x, tid = threadIdx.x;
  int i = b * 1024 + tid;
  int v = (i < NT) ? cnt[i] : 0;
  s[tid] = v;
  __syncthreads();
  for (int off = 1; off < 1024; off <<= 1){
    int t = (tid >= off) ? s[tid - off] : 0;
    __syncthreads();
    s[tid] += t;
    __syncthreads();
  }
  if (i < NT){
    int ex = s[tid] - v + part[b];
    R[i] = ex;
    cur[i] = ex;
  }
}

__global__ void k_scatter(const int* __restrict__ ei, int* __restrict__ cur,
                          int* __restrict__ col){
  long long i = (long long)blockIdx.x * blockDim.x + threadIdx.x;
  if (i >= 4LL * NEDGE) return;
  int t = (int)(i / NEDGE);
  int e = (int)(i - (long long)t * NEDGE);
  const int toff[4] = {0, N_CLAIM, 2*N_CLAIM, 2*N_CLAIM + N_ENTITY};
  int src = ei[(long long)t * 2 * NEDGE + e];
  int dst = ei[(long long)t * 2 * NEDGE + NEDGE + e];
  int pos = atomicAdd(cur + toff[t] + dst, 1);
  col[pos] = src;
}

// ---- mean aggregation: wave per dst node, lane = feature; bf16 in, fp32 accum, bf16 out ----
__global__ void k_agg(const unsigned short* __restrict__ X,
                      const int* __restrict__ R,
                      const int* __restrict__ col,
                      unsigned short* __restrict__ Mean,
                      int toff, int ndst){
  int w = (int)(((unsigned)blockIdx.x * blockDim.x + threadIdx.x) >> 6);
  int lane = threadIdx.x & 63;
  if (w >= ndst) return;
  int beg = R[toff + w];
  int end = R[toff + w + 1];
  float sum = 0.f;
  int p = beg;
  for (; p + 4 <= end; p += 4){
    int s0 = col[p], s1 = col[p+1], s2 = col[p+2], s3 = col[p+3];
    float a = b2f(X[(long long)s0 * F + lane]);
    float b = b2f(X[(long long)s1 * F + lane]);
    float c = b2f(X[(long long)s2 * F + lane]);
    float d = b2f(X[(long long)s3 * F + lane]);
    sum += (a + b) + (c + d);
  }
  for (; p < end; ++p) sum += b2f(X[(long long)col[p] * F + lane]);
  int c = end - beg;
  float m = (c > 0) ? sum * (1.0f / (float)c) : 0.f;
  Mean[(long long)w * F + lane] = f2b(m);
}

// ---- fused multi-source GEMM: H = act(sum_j Aj@Wj + bias); A bf16, W fp32->bf16 LDS ----
typedef __bf16 bf16x8 __attribute__((ext_vector_type(8)));
typedef float  f32x4  __attribute__((ext_vector_type(4)));
#define WT_STRIDE 72   // 144B rows: 16B-aligned for ds_read_b128, 2-way bank aliasing (free)

__global__ __launch_bounds__(256) void k_gemm(
    const unsigned short* __restrict__ A0, const unsigned short* __restrict__ A1,
    const unsigned short* __restrict__ A2, const unsigned short* __restrict__ A3,
    const float* __restrict__ W0, const float* __restrict__ W1,
    const float* __restrict__ W2, const float* __restrict__ W3,
    const float* __restrict__ b0, const float* __restrict__ b1,
    unsigned short* __restrict__ Hout, int M, int ns, int relu)
{
  __shared__ __align__(16) unsigned short WT[4 * 64 * WT_STRIDE]; // 36 KB
  const float* Ws[4] = {W0, W1, W2, W3};
  const unsigned short* As[4] = {A0, A1, A2, A3};
  int tid = threadIdx.x;
  for (int j = 0; j < ns; j++){
    const float* Wj = Ws[j];
    #pragma unroll
    for (int q = 0; q < 16; q++){
      int idx = q * 256 + tid;          // idx = k*64 + n (W row-major [k][n])
      int k = idx >> 6, n = idx & 63;
      WT[j * 64 * WT_STRIDE + n * WT_STRIDE + k] = f2b(Wj[idx]);
    }
  }
  __syncthreads();
  int wave = tid >> 6, lane = tid & 63;
  int quad = lane >> 4, l16 = lane & 15;
  int m0 = blockIdx.x * 64 + wave * 16;
  int arow = m0 + l16; if (arow >= M) arow = M - 1;   // clamp; stores guarded
  f32x4 z = {0.f, 0.f, 0.f, 0.f};
  f32x4 acc[4] = {z, z, z, z};
  for (int j = 0; j < ns; j++){
    const unsigned short* Aj = As[j];
    #pragma unroll
    for (int kk = 0; kk < 64; kk += 32){
      bf16x8 af = *(const bf16x8*)(Aj + (long long)arow * F + kk + quad * 8);
      #pragma unroll
      for (int c = 0; c < 4; c++){
        const unsigned short* bp = &WT[j * 64 * WT_STRIDE + (c * 16 + l16) * WT_STRIDE + kk + quad * 8];
        bf16x8 bfr = *(const bf16x8*)bp;
        acc[c] = __builtin_amdgcn_mfma_f32_16x16x32_bf16(af, bfr, acc[c], 0, 0, 0);
      }
    }
  }
  #pragma unroll
  for (int c = 0; c < 4; c++){
    int n = c * 16 + l16;
    float bv = b0[n] + (b1 ? b1[n] : 0.f);
    #pragma unroll
    for (int r = 0; r < 4; r++){
      int row = m0 + quad * 4 + r;
      if (row < M){
        float v = acc[c][r] + bv;
        if (relu) v = fmaxf(v, 0.f);
        Hout[(long long)row * F + n] = f2b(v);
      }
    }
  }
}

// ---------------- final classifier: wave per batch row; fp32 out ----------------
__global__ void k_out(const unsigned short* __restrict__ h2,
                      const int* __restrict__ cbi,
                      const float* __restrict__ Wc,
                      const float* __restrict__ bcp,
                      float* __restrict__ out){
  int w = (int)(((unsigned)blockIdx.x * blockDim.x + threadIdx.x) >> 6);
  int lane = threadIdx.x & 63;
  if (w >= BATCH) return;
  int c = cbi[w];
  float v = b2f(h2[(long long)c * F + lane]);
  float p0 = v * Wc[lane * 2];
  float p1 = v * Wc[lane * 2 + 1];
  for (int off = 32; off; off >>= 1){
    p0 += __shfl_xor(p0, off, 64);
    p1 += __shfl_xor(p1, off, 64);
  }
  if (lane == 0){
    out[2 * w]     = p0 + bcp[0];
    out[2 * w + 1] = p1 + bcp[1];
  }
}

extern "C" void kernel_launch(void* const* d_in, const int* in_sizes, int n_in,
                              void* d_out, int out_size, void* d_ws, size_t ws_size,
                              hipStream_t stream)
{
  const float* x_c = (const float*)d_in[0];
  const float* x_e = (const float*)d_in[1];
  const float* x_v = (const float*)d_in[2];
  const int*   ei  = (const int*)d_in[3];
  const int*   cbi = (const int*)d_in[4];
  const float* Wl1 = (const float*)d_in[5];
  const float* bl1 = (const float*)d_in[6];
  const float* Wr1 = (const float*)d_in[7];
  const float* Wl2 = (const float*)d_in[8];
  const float* bl2 = (const float*)d_in[9];
  const float* Wr2 = (const float*)d_in[10];
  const float* Wc  = (const float*)d_in[11];
  const float* bc  = (const float*)d_in[12];
  float* out = (float*)d_out;

  char* ws = (char*)d_ws;
  size_t off = 0;
  auto alloc = [&](size_t bytes) -> char* {
    char* p = ws + off;
    off += (bytes + 255) & ~(size_t)255;
    return p;
  };
  int* cnt  = (int*)alloc((size_t)NT * 4);
  int* R    = (int*)alloc((size_t)(NT + 1) * 4);
  int* cur  = (int*)alloc((size_t)NT * 4);
  int* part = (int*)alloc(1024 * 4);
  int* col  = (int*)alloc((size_t)4 * NEDGE * 4);
  unsigned short* xb_c  = (unsigned short*)alloc((size_t)N_CLAIM    * F * 2);
  unsigned short* xb_e  = (unsigned short*)alloc((size_t)N_ENTITY   * F * 2);
  unsigned short* xb_v  = (unsigned short*)alloc((size_t)N_EVIDENCE * F * 2);
  unsigned short* mean0 = (unsigned short*)alloc((size_t)N_CLAIM    * F * 2);
  unsigned short* mean1 = (unsigned short*)alloc((size_t)N_CLAIM    * F * 2);
  unsigned short* mean2 = (unsigned short*)alloc((size_t)N_ENTITY   * F * 2);
  unsigned short* mean3 = (unsigned short*)alloc((size_t)N_EVIDENCE * F * 2);
  unsigned short* h1c   = (unsigned short*)alloc((size_t)N_CLAIM    * F * 2);
  unsigned short* h1e   = (unsigned short*)alloc((size_t)N_ENTITY   * F * 2);
  unsigned short* h1v   = (unsigned short*)alloc((size_t)N_EVIDENCE * F * 2);
  unsigned short* h2c   = mean2;   // mean2 dead after layer-1 entity GEMM

  hipMemsetAsync(cnt, 0, (size_t)NT * 4, stream);

  // casts (independent of CSR build)
  k_cast<<<(N_CLAIM    * F / 4 + 255) / 256, 256, 0, stream>>>(x_c, xb_c, N_CLAIM    * F / 4);
  k_cast<<<(N_ENTITY   * F / 4 + 255) / 256, 256, 0, stream>>>(x_e, xb_e, N_ENTITY   * F / 4);
  k_cast<<<(N_EVIDENCE * F / 4 + 255) / 256, 256, 0, stream>>>(x_v, xb_v, N_EVIDENCE * F / 4);

  int blocksE = (int)((4LL * NEDGE + 255) / 256);
  k_hist<<<blocksE, 256, 0, stream>>>(ei, cnt);
  k_blocksum<<<NB_SCAN, 256, 0, stream>>>(cnt, part);
  k_scanpart<<<1, 1024, 0, stream>>>(part, R);
  k_scanfinal<<<NB_SCAN, 1024, 0, stream>>>(cnt, part, R, cur);
  k_scatter<<<blocksE, 256, 0, stream>>>(ei, cur, col);

  // ---- layer 1 aggregation (mean over incoming edges) ----
  k_agg<<<(N_CLAIM + 3) / 4,    256, 0, stream>>>(xb_e, R, col, mean0, 0,                      N_CLAIM);
  k_agg<<<(N_CLAIM + 3) / 4,    256, 0, stream>>>(xb_v, R, col, mean1, N_CLAIM,                N_CLAIM);
  k_agg<<<(N_ENTITY + 3) / 4,   256, 0, stream>>>(xb_c, R, col, mean2, 2 * N_CLAIM,            N_ENTITY);
  k_agg<<<(N_EVIDENCE + 3) / 4, 256, 0, stream>>>(xb_c, R, col, mean3, 2 * N_CLAIM + N_ENTITY, N_EVIDENCE);

  // ---- layer 1 transforms (fused bias + relu) ----
  k_gemm<<<(N_CLAIM + 63) / 64, 256, 0, stream>>>(mean0, mean1, xb_c, xb_c,
        Wl1, Wl1 + 4096, Wr1, Wr1 + 4096, bl1, bl1 + 64, h1c, N_CLAIM, 4, 1);
  k_gemm<<<(N_ENTITY + 63) / 64, 256, 0, stream>>>(mean2, xb_e, nullptr, nullptr,
        Wl1 + 2 * 4096, Wr1 + 2 * 4096, nullptr, nullptr, bl1 + 128, nullptr, h1e, N_ENTITY, 2, 1);
  k_gemm<<<(N_EVIDENCE + 63) / 64, 256, 0, stream>>>(mean3, xb_v, nullptr, nullptr,
        Wl1 + 3 * 4096, Wr1 + 3 * 4096, nullptr, nullptr, bl1 + 192, nullptr, h1v, N_EVIDENCE, 2, 1);

  // ---- layer 2: only claim outputs are consumed -> only edge types 0,1 ----
  k_agg<<<(N_CLAIM + 3) / 4, 256, 0, stream>>>(h1e, R, col, mean0, 0,       N_CLAIM);
  k_agg<<<(N_CLAIM + 3) / 4, 256, 0, stream>>>(h1v, R, col, mean1, N_CLAIM, N_CLAIM);
  k_gemm<<<(N_CLAIM + 63) / 64, 256, 0, stream>>>(mean0, mean1, h1c, h1c,
        Wl2, Wl2 + 4096, Wr2, Wr2 + 4096, bl2, bl2 + 64, h2c, N_CLAIM, 4, 0);

  // ---- classifier ----
  k_out<<<(BATCH * 64 + 255) / 256, 256, 0, stream>>>(h2c, cbi, Wc, bc, out);
}

// Round 3
// 913.054 us; speedup vs baseline: 1.9113x; 1.9113x over previous
//
#include <hip/hip_runtime.h>
#include <hip/hip_bf16.h>
#include <stdint.h>

#define N_CLAIM    100000
#define N_ENTITY   200000
#define N_EVIDENCE 150000
#define NEDGE      2000000
#define F          64
#define NT         550000      // concat dst: t0 claim [0,100K) t1 claim [100K,200K) t2 ent [200K,400K) t3 evid [400K,550K)
#define BATCH      50000

#define BSH   10               // bucket = gdst >> 10 (1024 nodes/bucket)
#define NBKT  538              // ceil(550000/1024)
#define CAP   24576            // max bucket mean 20480 (claims, lambda=20), sigma~143 -> +28 sigma pad
#define B3_BLOCKS 512
#define B3_CHUNK  16384        // 512*16384 = 8,388,608 >= 8M edges

static __device__ __forceinline__ float b2f(unsigned short u){
  return __uint_as_float(((unsigned int)u) << 16);
}
static __device__ __forceinline__ unsigned short f2b(float f){
  unsigned int x = __float_as_uint(f);
  x += 0x7fffu + ((x >> 16) & 1u);   // RNE
  return (unsigned short)(x >> 16);
}

// ---------------- fp32 -> bf16 cast ----------------
__global__ void k_cast(const float* __restrict__ in, unsigned short* __restrict__ out, int n4){
  int i = blockIdx.x * blockDim.x + threadIdx.x;
  if (i >= n4) return;
  float4 v = ((const float4*)in)[i];
  ushort4 o;
  o.x = f2b(v.x); o.y = f2b(v.y); o.z = f2b(v.z); o.w = f2b(v.w);
  ((ushort4*)out)[i] = o;
}

// ---------------- CSR build: partitioned counting sort ----------------
__global__ void k_init(int* __restrict__ cursor){
  int i = blockIdx.x * blockDim.x + threadIdx.x;
  if (i < NBKT) cursor[i] = i * CAP;
}

// block-level LDS histogram over coarse buckets -> one global reservation per (block,bucket)
// -> append packed (localdst<<18 | src) into padded per-bucket regions
__global__ __launch_bounds__(256) void k_bscatter(const int* __restrict__ ei,
                                                  int* __restrict__ cursor,
                                                  unsigned int* __restrict__ pairs){
  __shared__ int hcnt[NBKT];
  __shared__ int hpos[NBKT];
  const int toff[4] = {0, N_CLAIM, 2*N_CLAIM, 2*N_CLAIM + N_ENTITY};
  int tid = threadIdx.x;
  int g0 = blockIdx.x * B3_CHUNK;
  for (int b = tid; b < NBKT; b += 256) hcnt[b] = 0;
  __syncthreads();
  // pass 1: count
  #pragma unroll 4
  for (int k = 0; k < B3_CHUNK / 256; ++k){
    int g = g0 + k * 256 + tid;
    if (g < 4 * NEDGE){
      int t = g / NEDGE;
      int e = g - t * NEDGE;
      int dst = ei[t * 2 * NEDGE + NEDGE + e];
      int gdst = dst + toff[t];
      atomicAdd(&hcnt[gdst >> BSH], 1);
    }
  }
  __syncthreads();
  // reserve: one global atomic per (block, bucket)
  for (int b = tid; b < NBKT; b += 256){
    int c = hcnt[b];
    hpos[b] = c ? atomicAdd(&cursor[b], c) : 0;
  }
  __syncthreads();
  // pass 2: place (dst re-read hits L1/L2)
  #pragma unroll 4
  for (int k = 0; k < B3_CHUNK / 256; ++k){
    int g = g0 + k * 256 + tid;
    if (g < 4 * NEDGE){
      int t = g / NEDGE;
      int e = g - t * NEDGE;
      int dst = ei[t * 2 * NEDGE + NEDGE + e];
      int src = ei[t * 2 * NEDGE + e];
      int gdst = dst + toff[t];
      int off = atomicAdd(&hpos[gdst >> BSH], 1);
      pairs[off] = ((unsigned int)(gdst & ((1 << BSH) - 1)) << 18) | (unsigned int)src;
    }
  }
}

// scan bucket counts -> compact col bases; R[NT] = total
__global__ void k_bscan(const int* __restrict__ cursor, int* __restrict__ colBase,
                        int* __restrict__ R){
  __shared__ int s[1024];
  int tid = threadIdx.x;
  int c = (tid < NBKT) ? (cursor[tid] - tid * CAP) : 0;
  s[tid] = c;
  __syncthreads();
  for (int off = 1; off < 1024; off <<= 1){
    int t = (tid >= off) ? s[tid - off] : 0;
    __syncthreads();
    s[tid] += t;
    __syncthreads();
  }
  if (tid < NBKT) colBase[tid] = s[tid] - c;   // exclusive
  if (tid == 1023) R[NT] = s[1023];            // total (= 4*NEDGE)
}

// per bucket: LDS hist over 1024 local nodes + LDS scan -> R, then local scatter -> col
__global__ __launch_bounds__(256) void k_csr(const unsigned int* __restrict__ pairs,
                                             const int* __restrict__ cursor,
                                             const int* __restrict__ colBase,
                                             int* __restrict__ R, int* __restrict__ col){
  __shared__ int h[1024];
  __shared__ int aux[256];
  int b = blockIdx.x, tid = threadIdx.x;
  int cnt   = cursor[b] - b * CAP;
  int base  = colBase[b];
  int pbase = b * CAP;
  for (int j = tid; j < 1024; j += 256) h[j] = 0;
  __syncthreads();
  for (int i = tid; i < cnt; i += 256)
    atomicAdd(&h[pairs[pbase + i] >> 18], 1);
  __syncthreads();
  // exclusive scan of h[1024]: 4 per thread + 256-wide Hillis-Steele
  int j4 = tid * 4;
  int a0 = h[j4], a1 = h[j4+1], a2 = h[j4+2], a3 = h[j4+3];
  int tsum = a0 + a1 + a2 + a3;
  aux[tid] = tsum;
  __syncthreads();
  for (int off = 1; off < 256; off <<= 1){
    int t = (tid >= off) ? aux[tid - off] : 0;
    __syncthreads();
    aux[tid] += t;
    __syncthreads();
  }
  int ex = aux[tid] - tsum;
  h[j4]   = ex;
  h[j4+1] = ex + a0;
  h[j4+2] = ex + a0 + a1;
  h[j4+3] = ex + a0 + a1 + a2;
  int nodeBase = b << BSH;
  #pragma unroll
  for (int k = 0; k < 4; k++){
    int n = nodeBase + j4 + k;
    if (n < NT) R[n] = base + h[j4 + k];
  }
  __syncthreads();
  // place: col writes land in a ~cnt*4B L2-resident window
  for (int i = tid; i < cnt; i += 256){
    unsigned int p = pairs[pbase + i];
    int r = atomicAdd(&h[p >> 18], 1);
    col[base + r] = (int)(p & 0x3FFFFu);
  }
}

// ---- mean aggregation: wave per dst node, lane = feature; bf16 in, fp32 accum, bf16 out ----
__global__ void k_agg(const unsigned short* __restrict__ X,
                      const int* __restrict__ R,
                      const int* __restrict__ col,
                      unsigned short* __restrict__ Mean,
                      int toff, int ndst){
  int w = (int)(((unsigned)blockIdx.x * blockDim.x + threadIdx.x) >> 6);
  int lane = threadIdx.x & 63;
  if (w >= ndst) return;
  int beg = R[toff + w];
  int end = R[toff + w + 1];
  float sum = 0.f;
  int p = beg;
  for (; p + 4 <= end; p += 4){
    int s0 = col[p], s1 = col[p+1], s2 = col[p+2], s3 = col[p+3];
    float a = b2f(X[(long long)s0 * F + lane]);
    float b = b2f(X[(long long)s1 * F + lane]);
    float c = b2f(X[(long long)s2 * F + lane]);
    float d = b2f(X[(long long)s3 * F + lane]);
    sum += (a + b) + (c + d);
  }
  for (; p < end; ++p) sum += b2f(X[(long long)col[p] * F + lane]);
  int c = end - beg;
  float m = (c > 0) ? sum * (1.0f / (float)c) : 0.f;
  Mean[(long long)w * F + lane] = f2b(m);
}

// ---- fused multi-source GEMM: H = act(sum_j Aj@Wj + bias); A bf16, W fp32->bf16 LDS ----
typedef __bf16 bf16x8 __attribute__((ext_vector_type(8)));
typedef float  f32x4  __attribute__((ext_vector_type(4)));
#define WT_STRIDE 72   // 144B rows: 16B-aligned for ds_read_b128, 2-way bank aliasing (free)

__global__ __launch_bounds__(256) void k_gemm(
    const unsigned short* __restrict__ A0, const unsigned short* __restrict__ A1,
    const unsigned short* __restrict__ A2, const unsigned short* __restrict__ A3,
    const float* __restrict__ W0, const float* __restrict__ W1,
    const float* __restrict__ W2, const float* __restrict__ W3,
    const float* __restrict__ b0, const float* __restrict__ b1,
    unsigned short* __restrict__ Hout, int M, int ns, int relu)
{
  __shared__ __align__(16) unsigned short WT[4 * 64 * WT_STRIDE]; // 36 KB
  const float* Ws[4] = {W0, W1, W2, W3};
  const unsigned short* As[4] = {A0, A1, A2, A3};
  int tid = threadIdx.x;
  for (int j = 0; j < ns; j++){
    const float* Wj = Ws[j];
    #pragma unroll
    for (int q = 0; q < 16; q++){
      int idx = q * 256 + tid;          // idx = k*64 + n (W row-major [k][n])
      int k = idx >> 6, n = idx & 63;
      WT[j * 64 * WT_STRIDE + n * WT_STRIDE + k] = f2b(Wj[idx]);
    }
  }
  __syncthreads();
  int wave = tid >> 6, lane = tid & 63;
  int quad = lane >> 4, l16 = lane & 15;
  int m0 = blockIdx.x * 64 + wave * 16;
  int arow = m0 + l16; if (arow >= M) arow = M - 1;   // clamp; stores guarded
  f32x4 z = {0.f, 0.f, 0.f, 0.f};
  f32x4 acc[4] = {z, z, z, z};
  for (int j = 0; j < ns; j++){
    const unsigned short* Aj = As[j];
    #pragma unroll
    for (int kk = 0; kk < 64; kk += 32){
      bf16x8 af = *(const bf16x8*)(Aj + (long long)arow * F + kk + quad * 8);
      #pragma unroll
      for (int c = 0; c < 4; c++){
        const unsigned short* bp = &WT[j * 64 * WT_STRIDE + (c * 16 + l16) * WT_STRIDE + kk + quad * 8];
        bf16x8 bfr = *(const bf16x8*)bp;
        acc[c] = __builtin_amdgcn_mfma_f32_16x16x32_bf16(af, bfr, acc[c], 0, 0, 0);
      }
    }
  }
  #pragma unroll
  for (int c = 0; c < 4; c++){
    int n = c * 16 + l16;
    float bv = b0[n] + (b1 ? b1[n] : 0.f);
    #pragma unroll
    for (int r = 0; r < 4; r++){
      int row = m0 + quad * 4 + r;
      if (row < M){
        float v = acc[c][r] + bv;
        if (relu) v = fmaxf(v, 0.f);
        Hout[(long long)row * F + n] = f2b(v);
      }
    }
  }
}

// ---------------- final classifier: wave per batch row; fp32 out ----------------
__global__ void k_out(const unsigned short* __restrict__ h2,
                      const int* __restrict__ cbi,
                      const float* __restrict__ Wc,
                      const float* __restrict__ bcp,
                      float* __restrict__ out){
  int w = (int)(((unsigned)blockIdx.x * blockDim.x + threadIdx.x) >> 6);
  int lane = threadIdx.x & 63;
  if (w >= BATCH) return;
  int c = cbi[w];
  float v = b2f(h2[(long long)c * F + lane]);
  float p0 = v * Wc[lane * 2];
  float p1 = v * Wc[lane * 2 + 1];
  for (int off = 32; off; off >>= 1){
    p0 += __shfl_xor(p0, off, 64);
    p1 += __shfl_xor(p1, off, 64);
  }
  if (lane == 0){
    out[2 * w]     = p0 + bcp[0];
    out[2 * w + 1] = p1 + bcp[1];
  }
}

extern "C" void kernel_launch(void* const* d_in, const int* in_sizes, int n_in,
                              void* d_out, int out_size, void* d_ws, size_t ws_size,
                              hipStream_t stream)
{
  const float* x_c = (const float*)d_in[0];
  const float* x_e = (const float*)d_in[1];
  const float* x_v = (const float*)d_in[2];
  const int*   ei  = (const int*)d_in[3];
  const int*   cbi = (const int*)d_in[4];
  const float* Wl1 = (const float*)d_in[5];
  const float* bl1 = (const float*)d_in[6];
  const float* Wr1 = (const float*)d_in[7];
  const float* Wl2 = (const float*)d_in[8];
  const float* bl2 = (const float*)d_in[9];
  const float* Wr2 = (const float*)d_in[10];
  const float* Wc  = (const float*)d_in[11];
  const float* bc  = (const float*)d_in[12];
  float* out = (float*)d_out;

  char* ws = (char*)d_ws;
  size_t off = 0;
  auto alloc = [&](size_t bytes) -> char* {
    char* p = ws + off;
    off += (bytes + 255) & ~(size_t)255;
    return p;
  };
  int* R       = (int*)alloc((size_t)(NT + 1) * 4);
  int* cursor  = (int*)alloc((size_t)NBKT * 4);
  int* colBase = (int*)alloc((size_t)NBKT * 4);
  int* col     = (int*)alloc((size_t)4 * NEDGE * 4);
  unsigned int* pairs = (unsigned int*)alloc((size_t)NBKT * CAP * 4);   // 52.9 MB, dead after k_csr
  unsigned short* xb_c  = (unsigned short*)alloc((size_t)N_CLAIM    * F * 2);
  unsigned short* xb_e  = (unsigned short*)alloc((size_t)N_ENTITY   * F * 2);
  unsigned short* xb_v  = (unsigned short*)alloc((size_t)N_EVIDENCE * F * 2);
  unsigned short* mean0 = (unsigned short*)alloc((size_t)N_CLAIM    * F * 2);
  unsigned short* mean1 = (unsigned short*)alloc((size_t)N_CLAIM    * F * 2);
  unsigned short* h1c   = (unsigned short*)alloc((size_t)N_CLAIM    * F * 2);
  unsigned short* h1e   = (unsigned short*)alloc((size_t)N_ENTITY   * F * 2);
  unsigned short* h1v   = (unsigned short*)alloc((size_t)N_EVIDENCE * F * 2);
  // alias dead pairs region (52.9 MB) for mean2 (25.6) + mean3 (19.2); h2c reuses mean2
  unsigned short* mean2 = (unsigned short*)pairs;
  unsigned short* mean3 = (unsigned short*)((char*)pairs + (size_t)N_ENTITY * F * 2);
  unsigned short* h2c   = mean2;   // mean2 dead after layer-1 entity GEMM

  // casts (independent of CSR build)
  k_cast<<<(N_CLAIM    * F / 4 + 255) / 256, 256, 0, stream>>>(x_c, xb_c, N_CLAIM    * F / 4);
  k_cast<<<(N_ENTITY   * F / 4 + 255) / 256, 256, 0, stream>>>(x_e, xb_e, N_ENTITY   * F / 4);
  k_cast<<<(N_EVIDENCE * F / 4 + 255) / 256, 256, 0, stream>>>(x_v, xb_v, N_EVIDENCE * F / 4);

  // CSR build: bucketed counting sort
  k_init<<<(NBKT + 255) / 256, 256, 0, stream>>>(cursor);
  k_bscatter<<<B3_BLOCKS, 256, 0, stream>>>(ei, cursor, pairs);
  k_bscan<<<1, 1024, 0, stream>>>(cursor, colBase, R);
  k_csr<<<NBKT, 256, 0, stream>>>(pairs, cursor, colBase, R, col);

  // ---- layer 1 aggregation (mean over incoming edges) ----
  k_agg<<<(N_CLAIM + 3) / 4,    256, 0, stream>>>(xb_e, R, col, mean0, 0,                      N_CLAIM);
  k_agg<<<(N_CLAIM + 3) / 4,    256, 0, stream>>>(xb_v, R, col, mean1, N_CLAIM,                N_CLAIM);
  k_agg<<<(N_ENTITY + 3) / 4,   256, 0, stream>>>(xb_c, R, col, mean2, 2 * N_CLAIM,            N_ENTITY);
  k_agg<<<(N_EVIDENCE + 3) / 4, 256, 0, stream>>>(xb_c, R, col, mean3, 2 * N_CLAIM + N_ENTITY, N_EVIDENCE);

  // ---- layer 1 transforms (fused bias + relu) ----
  k_gemm<<<(N_CLAIM + 63) / 64, 256, 0, stream>>>(mean0, mean1, xb_c, xb_c,
        Wl1, Wl1 + 4096, Wr1, Wr1 + 4096, bl1, bl1 + 64, h1c, N_CLAIM, 4, 1);
  k_gemm<<<(N_ENTITY + 63) / 64, 256, 0, stream>>>(mean2, xb_e, nullptr, nullptr,
        Wl1 + 2 * 4096, Wr1 + 2 * 4096, nullptr, nullptr, bl1 + 128, nullptr, h1e, N_ENTITY, 2, 1);
  k_gemm<<<(N_EVIDENCE + 63) / 64, 256, 0, stream>>>(mean3, xb_v, nullptr, nullptr,
        Wl1 + 3 * 4096, Wr1 + 3 * 4096, nullptr, nullptr, bl1 + 192, nullptr, h1v, N_EVIDENCE, 2, 1);

  // ---- layer 2: only claim outputs are consumed -> only edge types 0,1 ----
  k_agg<<<(N_CLAIM + 3) / 4, 256, 0, stream>>>(h1e, R, col, mean0, 0,       N_CLAIM);
  k_agg<<<(N_CLAIM + 3) / 4, 256, 0, stream>>>(h1v, R, col, mean1, N_CLAIM, N_CLAIM);
  k_gemm<<<(N_CLAIM + 63) / 64, 256, 0, stream>>>(mean0, mean1, h1c, h1c,
        Wl2, Wl2 + 4096, Wr2, Wr2 + 4096, bl2, bl2 + 64, h2c, N_CLAIM, 4, 0);

  // ---- classifier ----
  k_out<<<(BATCH * 64 + 255) / 256, 256, 0, stream>>>(h2c, cbi, Wc, bc, out);
}

// Round 4
// 719.839 us; speedup vs baseline: 2.4243x; 1.2684x over previous
//
#include <hip/hip_runtime.h>
#include <hip/hip_bf16.h>
#include <stdint.h>

#define N_CLAIM    100000
#define N_ENTITY   200000
#define N_EVIDENCE 150000
#define NEDGE      2000000
#define F          64
#define NT         550000      // concat dst: t0 claim [0,100K) t1 claim [100K,200K) t2 ent [200K,400K) t3 evid [400K,550K)
#define BATCH      50000

#define BSH   10               // bucket = gdst >> 10 (1024 nodes/bucket)
#define NBKT  538              // ceil(550000/1024)
#define CAP   24576            // max bucket mean 20480 (claims), big sigma pad
#define B3_BLOCKS 1024
#define B3_CHUNK  8192         // 1024*8192 = 8,388,608 >= 8M edges

static __device__ __forceinline__ float b2f(unsigned short u){
  return __uint_as_float(((unsigned int)u) << 16);
}
static __device__ __forceinline__ unsigned short f2b(float f){
  unsigned int x = __float_as_uint(f);
  x += 0x7fffu + ((x >> 16) & 1u);   // RNE
  return (unsigned short)(x >> 16);
}

// ---------------- fp32 -> bf16 cast ----------------
__global__ void k_cast(const float* __restrict__ in, unsigned short* __restrict__ out, int n4){
  int i = blockIdx.x * blockDim.x + threadIdx.x;
  if (i >= n4) return;
  float4 v = ((const float4*)in)[i];
  ushort4 o;
  o.x = f2b(v.x); o.y = f2b(v.y); o.z = f2b(v.z); o.w = f2b(v.w);
  ((ushort4*)out)[i] = o;
}

// ---------------- used-claim mask ----------------
__global__ void k_mark(const int* __restrict__ cbi, int* __restrict__ flag){
  int i = blockIdx.x * blockDim.x + threadIdx.x;
  if (i < BATCH) flag[cbi[i]] = 1;
}

// ---------------- CSR build: partitioned counting sort ----------------
__global__ void k_init(int* __restrict__ cursor){
  int i = blockIdx.x * blockDim.x + threadIdx.x;
  if (i < NBKT) cursor[i] = i * CAP;
}

__global__ __launch_bounds__(256) void k_bscatter(const int* __restrict__ ei,
                                                  int* __restrict__ cursor,
                                                  unsigned int* __restrict__ pairs){
  __shared__ int hcnt[NBKT];
  __shared__ int hpos[NBKT];
  const int toff[4] = {0, N_CLAIM, 2*N_CLAIM, 2*N_CLAIM + N_ENTITY};
  int tid = threadIdx.x;
  int g0 = blockIdx.x * B3_CHUNK;
  for (int b = tid; b < NBKT; b += 256) hcnt[b] = 0;
  __syncthreads();
  #pragma unroll 4
  for (int k = 0; k < B3_CHUNK / 256; ++k){
    int g = g0 + k * 256 + tid;
    if (g < 4 * NEDGE){
      int t = g / NEDGE;
      int e = g - t * NEDGE;
      int dst = ei[t * 2 * NEDGE + NEDGE + e];
      atomicAdd(&hcnt[(dst + toff[t]) >> BSH], 1);
    }
  }
  __syncthreads();
  for (int b = tid; b < NBKT; b += 256){
    int c = hcnt[b];
    hpos[b] = c ? atomicAdd(&cursor[b], c) : 0;
  }
  __syncthreads();
  #pragma unroll 4
  for (int k = 0; k < B3_CHUNK / 256; ++k){
    int g = g0 + k * 256 + tid;
    if (g < 4 * NEDGE){
      int t = g / NEDGE;
      int e = g - t * NEDGE;
      int dst = ei[t * 2 * NEDGE + NEDGE + e];
      int src = ei[t * 2 * NEDGE + e];
      int gdst = dst + toff[t];
      int off = atomicAdd(&hpos[gdst >> BSH], 1);
      pairs[off] = ((unsigned int)(gdst & ((1 << BSH) - 1)) << 18) | (unsigned int)src;
    }
  }
}

__global__ void k_bscan(const int* __restrict__ cursor, int* __restrict__ colBase,
                        int* __restrict__ R){
  __shared__ int s[1024];
  int tid = threadIdx.x;
  int c = (tid < NBKT) ? (cursor[tid] - tid * CAP) : 0;
  s[tid] = c;
  __syncthreads();
  for (int off = 1; off < 1024; off <<= 1){
    int t = (tid >= off) ? s[tid - off] : 0;
    __syncthreads();
    s[tid] += t;
    __syncthreads();
  }
  if (tid < NBKT) colBase[tid] = s[tid] - c;
  if (tid == 1023) R[NT] = s[1023];
}

__global__ __launch_bounds__(256) void k_csr(const unsigned int* __restrict__ pairs,
                                             const int* __restrict__ cursor,
                                             const int* __restrict__ colBase,
                                             int* __restrict__ R, int* __restrict__ col){
  __shared__ int h[1024];
  __shared__ int aux[256];
  int b = blockIdx.x, tid = threadIdx.x;
  int cnt   = cursor[b] - b * CAP;
  int base  = colBase[b];
  int pbase = b * CAP;
  for (int j = tid; j < 1024; j += 256) h[j] = 0;
  __syncthreads();
  for (int i = tid; i < cnt; i += 256)
    atomicAdd(&h[pairs[pbase + i] >> 18], 1);
  __syncthreads();
  int j4 = tid * 4;
  int a0 = h[j4], a1 = h[j4+1], a2 = h[j4+2], a3 = h[j4+3];
  int tsum = a0 + a1 + a2 + a3;
  aux[tid] = tsum;
  __syncthreads();
  for (int off = 1; off < 256; off <<= 1){
    int t = (tid >= off) ? aux[tid - off] : 0;
    __syncthreads();
    aux[tid] += t;
    __syncthreads();
  }
  int ex = aux[tid] - tsum;
  h[j4]   = ex;
  h[j4+1] = ex + a0;
  h[j4+2] = ex + a0 + a1;
  h[j4+3] = ex + a0 + a1 + a2;
  int nodeBase = b << BSH;
  #pragma unroll
  for (int k = 0; k < 4; k++){
    int n = nodeBase + j4 + k;
    if (n < NT) R[n] = base + h[j4 + k];
  }
  __syncthreads();
  for (int i = tid; i < cnt; i += 256){
    unsigned int p = pairs[pbase + i];
    int r = atomicAdd(&h[p >> 18], 1);
    col[base + r] = (int)(p & 0x3FFFFu);
  }
}

// ---- mean aggregation: wave per dst node; 16 lanes x 8B per row, 4 rows/iter ----
// dst range [0, nd0+nd1): w < nd0 -> source X0, output M0 row w (flag fw=w);
//                         else      source X1, output M1 row (w-nd0).
// R indexed at Rbase + w (lists contiguous across the two sub-ranges).
__global__ __launch_bounds__(256) void k_agg(const unsigned short* __restrict__ X0,
                                             const unsigned short* __restrict__ X1,
                                             const int* __restrict__ R,
                                             const int* __restrict__ col,
                                             unsigned short* __restrict__ M0,
                                             unsigned short* __restrict__ M1,
                                             const int* __restrict__ flag,
                                             int Rbase, int nd0, int ndst){
  int w = (int)(((unsigned)blockIdx.x * blockDim.x + threadIdx.x) >> 6);
  if (w >= ndst) return;
  int lane = threadIdx.x & 63;
  int sub = lane >> 4;          // edge slot within quad
  int fl  = lane & 15;          // feature quad: features [4fl, 4fl+4)
  const unsigned short* X = X0;
  unsigned short* M = M0;
  int row = w;
  if (w >= nd0){ X = X1; M = M1; row = w - nd0; }
  if (flag && !flag[row]) return;
  int beg = R[Rbase + w];
  int end = R[Rbase + w + 1];
  int deg = end - beg;
  float4 s = {0.f, 0.f, 0.f, 0.f};
  int full = deg & ~3;
  int p = beg;
  #pragma unroll 2
  for (; p < beg + full; p += 4){
    int c = col[p + sub];                     // broadcast within 16-lane group
    ushort4 v = *(const ushort4*)(X + c * F + fl * 4);
    s.x += b2f(v.x); s.y += b2f(v.y); s.z += b2f(v.z); s.w += b2f(v.w);
  }
  int rem = deg - full;
  if (sub < rem){
    int c = col[p + sub];
    ushort4 v = *(const ushort4*)(X + c * F + fl * 4);
    s.x += b2f(v.x); s.y += b2f(v.y); s.z += b2f(v.z); s.w += b2f(v.w);
  }
  // reduce across the 4 edge-groups (lanes fl, fl+16, fl+32, fl+48)
  s.x += __shfl_xor(s.x, 16, 64); s.x += __shfl_xor(s.x, 32, 64);
  s.y += __shfl_xor(s.y, 16, 64); s.y += __shfl_xor(s.y, 32, 64);
  s.z += __shfl_xor(s.z, 16, 64); s.z += __shfl_xor(s.z, 32, 64);
  s.w += __shfl_xor(s.w, 16, 64); s.w += __shfl_xor(s.w, 32, 64);
  if (sub == 0){
    float r = (deg > 0) ? (1.0f / (float)deg) : 0.f;
    ushort4 o;
    o.x = f2b(s.x * r); o.y = f2b(s.y * r); o.z = f2b(s.z * r); o.w = f2b(s.w * r);
    *(ushort4*)(M + (long long)row * F + fl * 4) = o;
  }
}

// ---- fused multi-source GEMM: H = act(sum_j Aj@Wj + bias); A bf16, W fp32->bf16 LDS ----
typedef __bf16 bf16x8 __attribute__((ext_vector_type(8)));
typedef float  f32x4  __attribute__((ext_vector_type(4)));
#define WT_STRIDE 72

__global__ __launch_bounds__(256) void k_gemm(
    const unsigned short* __restrict__ A0, const unsigned short* __restrict__ A1,
    const unsigned short* __restrict__ A2, const unsigned short* __restrict__ A3,
    const float* __restrict__ W0, const float* __restrict__ W1,
    const float* __restrict__ W2, const float* __restrict__ W3,
    const float* __restrict__ b0, const float* __restrict__ b1,
    unsigned short* __restrict__ Hout, int M, int ns, int relu)
{
  __shared__ __align__(16) unsigned short WT[4 * 64 * WT_STRIDE];
  const float* Ws[4] = {W0, W1, W2, W3};
  const unsigned short* As[4] = {A0, A1, A2, A3};
  int tid = threadIdx.x;
  for (int j = 0; j < ns; j++){
    const float* Wj = Ws[j];
    #pragma unroll
    for (int q = 0; q < 16; q++){
      int idx = q * 256 + tid;
      int k = idx >> 6, n = idx & 63;
      WT[j * 64 * WT_STRIDE + n * WT_STRIDE + k] = f2b(Wj[idx]);
    }
  }
  __syncthreads();
  int wave = tid >> 6, lane = tid & 63;
  int quad = lane >> 4, l16 = lane & 15;
  int m0 = blockIdx.x * 64 + wave * 16;
  int arow = m0 + l16; if (arow >= M) arow = M - 1;
  f32x4 z = {0.f, 0.f, 0.f, 0.f};
  f32x4 acc[4] = {z, z, z, z};
  for (int j = 0; j < ns; j++){
    const unsigned short* Aj = As[j];
    #pragma unroll
    for (int kk = 0; kk < 64; kk += 32){
      bf16x8 af = *(const bf16x8*)(Aj + (long long)arow * F + kk + quad * 8);
      #pragma unroll
      for (int c = 0; c < 4; c++){
        const unsigned short* bp = &WT[j * 64 * WT_STRIDE + (c * 16 + l16) * WT_STRIDE + kk + quad * 8];
        bf16x8 bfr = *(const bf16x8*)bp;
        acc[c] = __builtin_amdgcn_mfma_f32_16x16x32_bf16(af, bfr, acc[c], 0, 0, 0);
      }
    }
  }
  #pragma unroll
  for (int c = 0; c < 4; c++){
    int n = c * 16 + l16;
    float bv = b0[n] + (b1 ? b1[n] : 0.f);
    #pragma unroll
    for (int r = 0; r < 4; r++){
      int row = m0 + quad * 4 + r;
      if (row < M){
        float v = acc[c][r] + bv;
        if (relu) v = fmaxf(v, 0.f);
        Hout[(long long)row * F + n] = f2b(v);
      }
    }
  }
}

// ---------------- final classifier: wave per batch row; fp32 out ----------------
__global__ void k_out(const unsigned short* __restrict__ h2,
                      const int* __restrict__ cbi,
                      const float* __restrict__ Wc,
                      const float* __restrict__ bcp,
                      float* __restrict__ out){
  int w = (int)(((unsigned)blockIdx.x * blockDim.x + threadIdx.x) >> 6);
  int lane = threadIdx.x & 63;
  if (w >= BATCH) return;
  int c = cbi[w];
  float v = b2f(h2[(long long)c * F + lane]);
  float p0 = v * Wc[lane * 2];
  float p1 = v * Wc[lane * 2 + 1];
  for (int off = 32; off; off >>= 1){
    p0 += __shfl_xor(p0, off, 64);
    p1 += __shfl_xor(p1, off, 64);
  }
  if (lane == 0){
    out[2 * w]     = p0 + bcp[0];
    out[2 * w + 1] = p1 + bcp[1];
  }
}

extern "C" void kernel_launch(void* const* d_in, const int* in_sizes, int n_in,
                              void* d_out, int out_size, void* d_ws, size_t ws_size,
                              hipStream_t stream)
{
  const float* x_c = (const float*)d_in[0];
  const float* x_e = (const float*)d_in[1];
  const float* x_v = (const float*)d_in[2];
  const int*   ei  = (const int*)d_in[3];
  const int*   cbi = (const int*)d_in[4];
  const float* Wl1 = (const float*)d_in[5];
  const float* bl1 = (const float*)d_in[6];
  const float* Wr1 = (const float*)d_in[7];
  const float* Wl2 = (const float*)d_in[8];
  const float* bl2 = (const float*)d_in[9];
  const float* Wr2 = (const float*)d_in[10];
  const float* Wc  = (const float*)d_in[11];
  const float* bc  = (const float*)d_in[12];
  float* out = (float*)d_out;

  char* ws = (char*)d_ws;
  size_t off = 0;
  auto alloc = [&](size_t bytes) -> char* {
    char* p = ws + off;
    off += (bytes + 255) & ~(size_t)255;
    return p;
  };
  int* R       = (int*)alloc((size_t)(NT + 1) * 4);
  int* cursor  = (int*)alloc((size_t)NBKT * 4);
  int* colBase = (int*)alloc((size_t)NBKT * 4);
  int* flag    = (int*)alloc((size_t)N_CLAIM * 4);
  int* col     = (int*)alloc((size_t)4 * NEDGE * 4);
  unsigned int* pairs = (unsigned int*)alloc((size_t)NBKT * CAP * 4);   // dead after k_csr
  unsigned short* xb_c  = (unsigned short*)alloc((size_t)N_CLAIM    * F * 2);
  unsigned short* xb_e  = (unsigned short*)alloc((size_t)N_ENTITY   * F * 2);
  unsigned short* xb_v  = (unsigned short*)alloc((size_t)N_EVIDENCE * F * 2);
  unsigned short* mean0 = (unsigned short*)alloc((size_t)N_CLAIM    * F * 2);
  unsigned short* mean1 = (unsigned short*)alloc((size_t)N_CLAIM    * F * 2);
  unsigned short* h1c   = (unsigned short*)alloc((size_t)N_CLAIM    * F * 2);
  unsigned short* h1e   = (unsigned short*)alloc((size_t)N_ENTITY   * F * 2);
  unsigned short* h1v   = (unsigned short*)alloc((size_t)N_EVIDENCE * F * 2);
  unsigned short* mean2 = (unsigned short*)pairs;   // alias dead pairs region
  unsigned short* mean3 = (unsigned short*)((char*)pairs + (size_t)N_ENTITY * F * 2);
  unsigned short* h2c   = mean2;                    // mean2 dead after entity GEMM

  hipMemsetAsync(flag, 0, (size_t)N_CLAIM * 4, stream);

  k_cast<<<(N_CLAIM    * F / 4 + 255) / 256, 256, 0, stream>>>(x_c, xb_c, N_CLAIM    * F / 4);
  k_cast<<<(N_ENTITY   * F / 4 + 255) / 256, 256, 0, stream>>>(x_e, xb_e, N_ENTITY   * F / 4);
  k_cast<<<(N_EVIDENCE * F / 4 + 255) / 256, 256, 0, stream>>>(x_v, xb_v, N_EVIDENCE * F / 4);
  k_mark<<<(BATCH + 255) / 256, 256, 0, stream>>>(cbi, flag);

  k_init<<<(NBKT + 255) / 256, 256, 0, stream>>>(cursor);
  k_bscatter<<<B3_BLOCKS, 256, 0, stream>>>(ei, cursor, pairs);
  k_bscan<<<1, 1024, 0, stream>>>(cursor, colBase, R);
  k_csr<<<NBKT, 256, 0, stream>>>(pairs, cursor, colBase, R, col);

  // ---- layer 1 aggregation ----
  // claims (types 0,1), flagged-only:
  k_agg<<<(2 * N_CLAIM * 64 + 255) / 256, 256, 0, stream>>>(
      xb_e, xb_v, R, col, mean0, mean1, flag, 0, N_CLAIM, 2 * N_CLAIM);
  // entity + evidence (both source xb_c):
  k_agg<<<((N_ENTITY + N_EVIDENCE) * 64 + 255) / 256, 256, 0, stream>>>(
      xb_c, xb_c, R, col, mean2, mean3, nullptr, 2 * N_CLAIM, N_ENTITY, N_ENTITY + N_EVIDENCE);

  // ---- layer 1 transforms ----
  k_gemm<<<(N_CLAIM + 63) / 64, 256, 0, stream>>>(mean0, mean1, xb_c, xb_c,
        Wl1, Wl1 + 4096, Wr1, Wr1 + 4096, bl1, bl1 + 64, h1c, N_CLAIM, 4, 1);
  k_gemm<<<(N_ENTITY + 63) / 64, 256, 0, stream>>>(mean2, xb_e, nullptr, nullptr,
        Wl1 + 2 * 4096, Wr1 + 2 * 4096, nullptr, nullptr, bl1 + 128, nullptr, h1e, N_ENTITY, 2, 1);
  k_gemm<<<(N_EVIDENCE + 63) / 64, 256, 0, stream>>>(mean3, xb_v, nullptr, nullptr,
        Wl1 + 3 * 4096, Wr1 + 3 * 4096, nullptr, nullptr, bl1 + 192, nullptr, h1v, N_EVIDENCE, 2, 1);

  // ---- layer 2: claims only, flagged-only ----
  k_agg<<<(2 * N_CLAIM * 64 + 255) / 256, 256, 0, stream>>>(
      h1e, h1v, R, col, mean0, mean1, flag, 0, N_CLAIM, 2 * N_CLAIM);
  k_gemm<<<(N_CLAIM + 63) / 64, 256, 0, stream>>>(mean0, mean1, h1c, h1c,
        Wl2, Wl2 + 4096, Wr2, Wr2 + 4096, bl2, bl2 + 64, h2c, N_CLAIM, 4, 0);

  // ---- classifier ----
  k_out<<<(BATCH * 64 + 255) / 256, 256, 0, stream>>>(h2c, cbi, Wc, bc, out);
}

// Round 5
// 669.613 us; speedup vs baseline: 2.6062x; 1.0750x over previous
//
#include <hip/hip_runtime.h>
#include <hip/hip_bf16.h>
#include <stdint.h>

#define N_CLAIM    100000
#define N_ENTITY   200000
#define N_EVIDENCE 150000
#define NEDGE      2000000
#define F          64
#define NT         550000      // concat dst: t0 claim [0,100K) t1 claim [100K,200K) t2 ent [200K,400K) t3 evid [400K,550K)
#define BATCH      50000

#define BSH   10
#define NBKT  538
#define CAP   24576
#define B3_BLOCKS 2048
#define B3_CHUNK  4096         // 2048*4096 = 8,388,608 >= 8M edges

static __device__ __forceinline__ float b2f(unsigned short u){
  return __uint_as_float(((unsigned int)u) << 16);
}
static __device__ __forceinline__ unsigned short f2b(float f){
  unsigned int x = __float_as_uint(f);
  x += 0x7fffu + ((x >> 16) & 1u);   // RNE
  return (unsigned short)(x >> 16);
}

// ---------------- fp32 -> bf16 cast ----------------
__global__ void k_cast(const float* __restrict__ in, unsigned short* __restrict__ out, int n4){
  int i = blockIdx.x * blockDim.x + threadIdx.x;
  if (i >= n4) return;
  float4 v = ((const float4*)in)[i];
  ushort4 o;
  o.x = f2b(v.x); o.y = f2b(v.y); o.z = f2b(v.z); o.w = f2b(v.w);
  ((ushort4*)out)[i] = o;
}

// ---------------- used-claim mask + compaction ----------------
__global__ void k_mark(const int* __restrict__ cbi, int* __restrict__ flag){
  int i = blockIdx.x * blockDim.x + threadIdx.x;
  if (i < BATCH) flag[cbi[i]] = 1;
}
__global__ void k_rank(const int* __restrict__ flag, int* __restrict__ rank,
                       int* __restrict__ list, int* __restrict__ nu){
  int i = blockIdx.x * blockDim.x + threadIdx.x;
  if (i < N_CLAIM && flag[i]){
    int r = atomicAdd(nu, 1);
    rank[i] = r;
    list[r] = i;
  }
}

// ---------------- CSR build: partitioned counting sort ----------------
__global__ void k_init(int* __restrict__ cursor){
  int i = blockIdx.x * blockDim.x + threadIdx.x;
  if (i < NBKT) cursor[i] = i * CAP;
}

__global__ __launch_bounds__(256) void k_bscatter(const int* __restrict__ ei,
                                                  int* __restrict__ cursor,
                                                  unsigned int* __restrict__ pairs){
  __shared__ int hcnt[NBKT];
  __shared__ int hpos[NBKT];
  const int toff[4] = {0, N_CLAIM, 2*N_CLAIM, 2*N_CLAIM + N_ENTITY};
  int tid = threadIdx.x;
  int g0 = blockIdx.x * B3_CHUNK;
  for (int b = tid; b < NBKT; b += 256) hcnt[b] = 0;
  __syncthreads();
  #pragma unroll 4
  for (int k = 0; k < B3_CHUNK / 256; ++k){
    int g = g0 + k * 256 + tid;
    if (g < 4 * NEDGE){
      int t = g / NEDGE;
      int e = g - t * NEDGE;
      int dst = ei[t * 2 * NEDGE + NEDGE + e];
      atomicAdd(&hcnt[(dst + toff[t]) >> BSH], 1);
    }
  }
  __syncthreads();
  for (int b = tid; b < NBKT; b += 256){
    int c = hcnt[b];
    hpos[b] = c ? atomicAdd(&cursor[b], c) : 0;
  }
  __syncthreads();
  #pragma unroll 4
  for (int k = 0; k < B3_CHUNK / 256; ++k){
    int g = g0 + k * 256 + tid;
    if (g < 4 * NEDGE){
      int t = g / NEDGE;
      int e = g - t * NEDGE;
      int dst = ei[t * 2 * NEDGE + NEDGE + e];
      int src = ei[t * 2 * NEDGE + e];
      int gdst = dst + toff[t];
      int off = atomicAdd(&hpos[gdst >> BSH], 1);
      pairs[off] = ((unsigned int)(gdst & ((1 << BSH) - 1)) << 18) | (unsigned int)src;
    }
  }
}

__global__ void k_bscan(const int* __restrict__ cursor, int* __restrict__ colBase,
                        int* __restrict__ R){
  __shared__ int s[1024];
  int tid = threadIdx.x;
  int c = (tid < NBKT) ? (cursor[tid] - tid * CAP) : 0;
  s[tid] = c;
  __syncthreads();
  for (int off = 1; off < 1024; off <<= 1){
    int t = (tid >= off) ? s[tid - off] : 0;
    __syncthreads();
    s[tid] += t;
    __syncthreads();
  }
  if (tid < NBKT) colBase[tid] = s[tid] - c;
  if (tid == 1023) R[NT] = s[1023];
}

__global__ __launch_bounds__(256) void k_csr(const unsigned int* __restrict__ pairs,
                                             const int* __restrict__ cursor,
                                             const int* __restrict__ colBase,
                                             int* __restrict__ R, int* __restrict__ col){
  __shared__ int h[1024];
  __shared__ int aux[256];
  int b = blockIdx.x, tid = threadIdx.x;
  int cnt   = cursor[b] - b * CAP;
  int base  = colBase[b];
  int pbase = b * CAP;
  for (int j = tid; j < 1024; j += 256) h[j] = 0;
  __syncthreads();
  for (int i = tid; i < cnt; i += 256)
    atomicAdd(&h[pairs[pbase + i] >> 18], 1);
  __syncthreads();
  int j4 = tid * 4;
  int a0 = h[j4], a1 = h[j4+1], a2 = h[j4+2], a3 = h[j4+3];
  int tsum = a0 + a1 + a2 + a3;
  aux[tid] = tsum;
  __syncthreads();
  for (int off = 1; off < 256; off <<= 1){
    int t = (tid >= off) ? aux[tid - off] : 0;
    __syncthreads();
    aux[tid] += t;
    __syncthreads();
  }
  int ex = aux[tid] - tsum;
  h[j4]   = ex;
  h[j4+1] = ex + a0;
  h[j4+2] = ex + a0 + a1;
  h[j4+3] = ex + a0 + a1 + a2;
  int nodeBase = b << BSH;
  #pragma unroll
  for (int k = 0; k < 4; k++){
    int n = nodeBase + j4 + k;
    if (n < NT) R[n] = base + h[j4 + k];
  }
  __syncthreads();
  for (int i = tid; i < cnt; i += 256){
    unsigned int p = pairs[pbase + i];
    int r = atomicAdd(&h[p >> 18], 1);
    col[base + r] = (int)(p & 0x3FFFFu);
  }
}

// ---- mean aggregation: 4 dst rows per wave, 16 lanes x 8B per row, no cross-row reduce ----
// job j: j < nd0 -> (X0, M0, node = RbA+row); else (X1, M1, node = RbB+row)
// row = list ? list[idx] : idx; output row = idx (compacted position).
__global__ __launch_bounds__(256) void k_agg(const unsigned short* __restrict__ X0,
                                             const unsigned short* __restrict__ X1,
                                             const int* __restrict__ R,
                                             const int* __restrict__ col,
                                             unsigned short* __restrict__ M0,
                                             unsigned short* __restrict__ M1,
                                             const int* __restrict__ list,
                                             const int* __restrict__ nu_ptr,
                                             int RbA, int RbB, int nd0_param, int njobs_param){
  int tid  = threadIdx.x;
  int lane = tid & 63;
  int g    = lane >> 4;          // row group 0..3
  int fl   = lane & 15;          // feature slot: features [4fl, 4fl+4)
  int wv   = (int)blockIdx.x * 4 + (tid >> 6);
  int nu     = list ? *nu_ptr : 0;
  int njobs  = list ? 2 * nu : njobs_param;
  int nd0    = list ? nu : nd0_param;
  int j = wv * 4 + g;
  bool active = j < njobs;
  int sub_t = 0, idx = 0, row = 0, node = 0;
  if (active){
    sub_t = (j >= nd0) ? 1 : 0;
    idx = j - (sub_t ? nd0 : 0);
    row = list ? list[idx] : idx;
    node = (sub_t ? RbB : RbA) + row;
  }
  const unsigned short* X = sub_t ? X1 : X0;
  unsigned short* Mo = sub_t ? M1 : M0;
  int rbeg = 0, rend = 0;
  if (active){ rbeg = R[node]; rend = R[node + 1]; }
  int deg = rend - rbeg;
  float4 acc = {0.f, 0.f, 0.f, 0.f};
  for (int p = rbeg; p < rend; p += 8){
    int nb = rend - p; if (nb > 8) nb = 8;
    int cid = 0;
    if (fl < nb) cid = col[p + fl];      // 1 coalesced id prefetch per 8 edges
    #pragma unroll
    for (int k = 0; k < 8; ++k){
      int c = __shfl(cid, (g << 4) + k, 64);
      if (k < nb){
        uint2 d = *(const uint2*)(X + c * F + fl * 4);
        acc.x += __uint_as_float(d.x << 16);
        acc.y += __uint_as_float(d.x & 0xffff0000u);
        acc.z += __uint_as_float(d.y << 16);
        acc.w += __uint_as_float(d.y & 0xffff0000u);
      }
    }
  }
  if (active){
    float r = deg ? (1.0f / (float)deg) : 0.f;
    ushort4 o;
    o.x = f2b(acc.x * r); o.y = f2b(acc.y * r);
    o.z = f2b(acc.z * r); o.w = f2b(acc.w * r);
    *(ushort4*)(Mo + (long long)idx * F + fl * 4) = o;
  }
}

// ---- fused multi-source GEMM: H = act(sum_j Aj@Wj + bias) ----
typedef __bf16 bf16x8 __attribute__((ext_vector_type(8)));
typedef float  f32x4  __attribute__((ext_vector_type(4)));
#define WT_STRIDE 72

__global__ __launch_bounds__(256) void k_gemm(
    const unsigned short* __restrict__ A0, const unsigned short* __restrict__ A1,
    const unsigned short* __restrict__ A2, const unsigned short* __restrict__ A3,
    const float* __restrict__ W0, const float* __restrict__ W1,
    const float* __restrict__ W2, const float* __restrict__ W3,
    const float* __restrict__ b0, const float* __restrict__ b1,
    unsigned short* __restrict__ Hout,
    const int* __restrict__ Alist, int amask,
    const int* __restrict__ Mptr, int Mparam, int ns, int relu)
{
  int M = Mptr ? *Mptr : Mparam;
  if ((int)blockIdx.x * 64 >= M) return;     // block-uniform early exit
  __shared__ __align__(16) unsigned short WT[4 * 64 * WT_STRIDE];
  const float* Ws[4] = {W0, W1, W2, W3};
  const unsigned short* As[4] = {A0, A1, A2, A3};
  int tid = threadIdx.x;
  for (int j = 0; j < ns; j++){
    const float* Wj = Ws[j];
    #pragma unroll
    for (int q = 0; q < 16; q++){
      int idx = q * 256 + tid;
      int k = idx >> 6, n = idx & 63;
      WT[j * 64 * WT_STRIDE + n * WT_STRIDE + k] = f2b(Wj[idx]);
    }
  }
  __syncthreads();
  int wave = tid >> 6, lane = tid & 63;
  int quad = lane >> 4, l16 = lane & 15;
  int m0 = blockIdx.x * 64 + wave * 16;
  int arow = m0 + l16; if (arow >= M) arow = M - 1;
  int arows[4];
  #pragma unroll
  for (int j = 0; j < 4; j++)
    arows[j] = ((amask >> j) & 1) ? Alist[arow] : arow;
  f32x4 z = {0.f, 0.f, 0.f, 0.f};
  f32x4 acc[4] = {z, z, z, z};
  for (int j = 0; j < ns; j++){
    const unsigned short* Aj = As[j];
    #pragma unroll
    for (int kk = 0; kk < 64; kk += 32){
      bf16x8 af = *(const bf16x8*)(Aj + (long long)arows[j] * F + kk + quad * 8);
      #pragma unroll
      for (int c = 0; c < 4; c++){
        const unsigned short* bp = &WT[j * 64 * WT_STRIDE + (c * 16 + l16) * WT_STRIDE + kk + quad * 8];
        bf16x8 bfr = *(const bf16x8*)bp;
        acc[c] = __builtin_amdgcn_mfma_f32_16x16x32_bf16(af, bfr, acc[c], 0, 0, 0);
      }
    }
  }
  #pragma unroll
  for (int c = 0; c < 4; c++){
    int n = c * 16 + l16;
    float bv = b0[n] + (b1 ? b1[n] : 0.f);
    #pragma unroll
    for (int r = 0; r < 4; r++){
      int row = m0 + quad * 4 + r;
      if (row < M){
        float v = acc[c][r] + bv;
        if (relu) v = fmaxf(v, 0.f);
        Hout[(long long)row * F + n] = f2b(v);
      }
    }
  }
}

// ---------------- final classifier: wave per batch row; fp32 out ----------------
__global__ void k_out(const unsigned short* __restrict__ h2,
                      const int* __restrict__ cbi,
                      const int* __restrict__ rank,
                      const float* __restrict__ Wc,
                      const float* __restrict__ bcp,
                      float* __restrict__ out){
  int w = (int)(((unsigned)blockIdx.x * blockDim.x + threadIdx.x) >> 6);
  int lane = threadIdx.x & 63;
  if (w >= BATCH) return;
  int rk = rank[cbi[w]];
  float v = b2f(h2[(long long)rk * F + lane]);
  float p0 = v * Wc[lane * 2];
  float p1 = v * Wc[lane * 2 + 1];
  for (int off = 32; off; off >>= 1){
    p0 += __shfl_xor(p0, off, 64);
    p1 += __shfl_xor(p1, off, 64);
  }
  if (lane == 0){
    out[2 * w]     = p0 + bcp[0];
    out[2 * w + 1] = p1 + bcp[1];
  }
}

extern "C" void kernel_launch(void* const* d_in, const int* in_sizes, int n_in,
                              void* d_out, int out_size, void* d_ws, size_t ws_size,
                              hipStream_t stream)
{
  const float* x_c = (const float*)d_in[0];
  const float* x_e = (const float*)d_in[1];
  const float* x_v = (const float*)d_in[2];
  const int*   ei  = (const int*)d_in[3];
  const int*   cbi = (const int*)d_in[4];
  const float* Wl1 = (const float*)d_in[5];
  const float* bl1 = (const float*)d_in[6];
  const float* Wr1 = (const float*)d_in[7];
  const float* Wl2 = (const float*)d_in[8];
  const float* bl2 = (const float*)d_in[9];
  const float* Wr2 = (const float*)d_in[10];
  const float* Wc  = (const float*)d_in[11];
  const float* bc  = (const float*)d_in[12];
  float* out = (float*)d_out;

  char* ws = (char*)d_ws;
  size_t off = 0;
  auto alloc = [&](size_t bytes) -> char* {
    char* p = ws + off;
    off += (bytes + 255) & ~(size_t)255;
    return p;
  };
  int* R       = (int*)alloc((size_t)(NT + 1) * 4);
  int* cursor  = (int*)alloc((size_t)NBKT * 4);
  int* colBase = (int*)alloc((size_t)NBKT * 4);
  int* flag    = (int*)alloc((size_t)N_CLAIM * 4);
  int* rank    = (int*)alloc((size_t)N_CLAIM * 4);
  int* list    = (int*)alloc((size_t)BATCH * 4);
  int* nu      = (int*)alloc(256);
  int* col     = (int*)alloc((size_t)4 * NEDGE * 4);
  unsigned int* pairs = (unsigned int*)alloc((size_t)NBKT * CAP * 4);   // dead after k_csr
  unsigned short* xb_c  = (unsigned short*)alloc((size_t)N_CLAIM    * F * 2);
  unsigned short* xb_e  = (unsigned short*)alloc((size_t)N_ENTITY   * F * 2);
  unsigned short* xb_v  = (unsigned short*)alloc((size_t)N_EVIDENCE * F * 2);
  unsigned short* mean0 = (unsigned short*)alloc((size_t)BATCH * F * 2);   // compacted
  unsigned short* mean1 = (unsigned short*)alloc((size_t)BATCH * F * 2);   // compacted
  unsigned short* h1c   = (unsigned short*)alloc((size_t)BATCH * F * 2);   // compacted
  unsigned short* h1e   = (unsigned short*)alloc((size_t)N_ENTITY   * F * 2);
  unsigned short* h1v   = (unsigned short*)alloc((size_t)N_EVIDENCE * F * 2);
  unsigned short* mean2 = (unsigned short*)pairs;   // alias dead pairs region
  unsigned short* mean3 = (unsigned short*)((char*)pairs + (size_t)N_ENTITY * F * 2);
  unsigned short* h2c   = mean2;                    // compacted; mean2 dead after entity GEMM

  hipMemsetAsync(flag, 0, (size_t)N_CLAIM * 4, stream);
  hipMemsetAsync(nu, 0, 4, stream);

  k_cast<<<(N_CLAIM    * F / 4 + 255) / 256, 256, 0, stream>>>(x_c, xb_c, N_CLAIM    * F / 4);
  k_cast<<<(N_ENTITY   * F / 4 + 255) / 256, 256, 0, stream>>>(x_e, xb_e, N_ENTITY   * F / 4);
  k_cast<<<(N_EVIDENCE * F / 4 + 255) / 256, 256, 0, stream>>>(x_v, xb_v, N_EVIDENCE * F / 4);
  k_mark<<<(BATCH + 255) / 256, 256, 0, stream>>>(cbi, flag);
  k_rank<<<(N_CLAIM + 255) / 256, 256, 0, stream>>>(flag, rank, list, nu);

  k_init<<<(NBKT + 255) / 256, 256, 0, stream>>>(cursor);
  k_bscatter<<<B3_BLOCKS, 256, 0, stream>>>(ei, cursor, pairs);
  k_bscan<<<1, 1024, 0, stream>>>(cursor, colBase, R);
  k_csr<<<NBKT, 256, 0, stream>>>(pairs, cursor, colBase, R, col);

  // ---- layer 1 aggregation ----
  // claims (types 0,1), compacted jobs (<= 2*BATCH):
  k_agg<<<(2 * BATCH + 15) / 16, 256, 0, stream>>>(
      xb_e, xb_v, R, col, mean0, mean1, list, nu, 0, N_CLAIM, 0, 0);
  // entity + evidence (both source xb_c):
  k_agg<<<(N_ENTITY + N_EVIDENCE + 15) / 16, 256, 0, stream>>>(
      xb_c, xb_c, R, col, mean2, mean3, nullptr, nullptr,
      2 * N_CLAIM, 2 * N_CLAIM + N_ENTITY, N_ENTITY, N_ENTITY + N_EVIDENCE);

  // ---- layer 1 transforms ----
  k_gemm<<<(BATCH + 63) / 64, 256, 0, stream>>>(mean0, mean1, xb_c, xb_c,
        Wl1, Wl1 + 4096, Wr1, Wr1 + 4096, bl1, bl1 + 64, h1c,
        list, 0b1100, nu, 0, 4, 1);
  k_gemm<<<(N_ENTITY + 63) / 64, 256, 0, stream>>>(mean2, xb_e, nullptr, nullptr,
        Wl1 + 2 * 4096, Wr1 + 2 * 4096, nullptr, nullptr, bl1 + 128, nullptr, h1e,
        nullptr, 0, nullptr, N_ENTITY, 2, 1);
  k_gemm<<<(N_EVIDENCE + 63) / 64, 256, 0, stream>>>(mean3, xb_v, nullptr, nullptr,
        Wl1 + 3 * 4096, Wr1 + 3 * 4096, nullptr, nullptr, bl1 + 192, nullptr, h1v,
        nullptr, 0, nullptr, N_EVIDENCE, 2, 1);

  // ---- layer 2: claims only, compacted ----
  k_agg<<<(2 * BATCH + 15) / 16, 256, 0, stream>>>(
      h1e, h1v, R, col, mean0, mean1, list, nu, 0, N_CLAIM, 0, 0);
  k_gemm<<<(BATCH + 63) / 64, 256, 0, stream>>>(mean0, mean1, h1c, h1c,
        Wl2, Wl2 + 4096, Wr2, Wr2 + 4096, bl2, bl2 + 64, h2c,
        nullptr, 0, nu, 0, 4, 0);

  // ---- classifier ----
  k_out<<<(BATCH * 64 + 255) / 256, 256, 0, stream>>>(h2c, cbi, rank, Wc, bc, out);
}

// Round 6
// 630.824 us; speedup vs baseline: 2.7664x; 1.0615x over previous
//
#include <hip/hip_runtime.h>
#include <hip/hip_bf16.h>
#include <stdint.h>

#define N_CLAIM    100000
#define N_ENTITY   200000
#define N_EVIDENCE 150000
#define NEDGE      2000000
#define F          64
#define NT         550000      // concat dst: t0 claim [0,100K) t1 claim [100K,200K) t2 ent [200K,400K) t3 evid [400K,550K)
#define BATCH      50000

#define BSH   10
#define NBKT  538
#define CAP   24576
#define B3_BLOCKS 1024
#define B3_CHUNK  8192         // 1024*8192 = 8,388,608 >= 8M edges

static __device__ __forceinline__ float b2f(unsigned short u){
  return __uint_as_float(((unsigned int)u) << 16);
}
static __device__ __forceinline__ unsigned short f2b(float f){
  unsigned int x = __float_as_uint(f);
  x += 0x7fffu + ((x >> 16) & 1u);   // RNE
  return (unsigned short)(x >> 16);
}

// ---------------- fp32 -> bf16 cast ----------------
__global__ void k_cast(const float* __restrict__ in, unsigned short* __restrict__ out, int n4){
  int i = blockIdx.x * blockDim.x + threadIdx.x;
  if (i >= n4) return;
  float4 v = ((const float4*)in)[i];
  ushort4 o;
  o.x = f2b(v.x); o.y = f2b(v.y); o.z = f2b(v.z); o.w = f2b(v.w);
  ((ushort4*)out)[i] = o;
}

// ---------------- used-claim mask + compaction ----------------
__global__ void k_mark(const int* __restrict__ cbi, int* __restrict__ flag){
  int i = blockIdx.x * blockDim.x + threadIdx.x;
  if (i < BATCH) flag[cbi[i]] = 1;
}
__global__ void k_rank(const int* __restrict__ flag, int* __restrict__ rank,
                       int* __restrict__ list, int* __restrict__ nu){
  int i = blockIdx.x * blockDim.x + threadIdx.x;
  if (i < N_CLAIM && flag[i]){
    int r = atomicAdd(nu, 1);
    rank[i] = r;
    list[r] = i;
  }
}

// ---------------- CSR build: partitioned counting sort ----------------
__global__ void k_init(int* __restrict__ cursor){
  int i = blockIdx.x * blockDim.x + threadIdx.x;
  if (i < NBKT) cursor[i] = i * CAP;
}

// pass1: load dst once, filter dead claim-dst edges via flag, cache gdst in LDS,
//        LDS bucket histogram; reserve per-bucket space with ONE global atomic each;
// pass2: src-only global load, gdst from LDS, append packed (localdst<<18 | src).
__global__ __launch_bounds__(256) void k_bscatter(const int* __restrict__ ei,
                                                  const int* __restrict__ flag,
                                                  int* __restrict__ cursor,
                                                  unsigned int* __restrict__ pairs){
  __shared__ int hcnt[NBKT];
  __shared__ int hpos[NBKT];
  __shared__ unsigned int ldst[B3_CHUNK];   // 32 KB: gdst, or ~0u = skip
  const int toff[4] = {0, N_CLAIM, 2*N_CLAIM, 2*N_CLAIM + N_ENTITY};
  int tid = threadIdx.x;
  int g0 = blockIdx.x * B3_CHUNK;
  for (int b = tid; b < NBKT; b += 256) hcnt[b] = 0;
  __syncthreads();
  #pragma unroll 4
  for (int k = 0; k < B3_CHUNK / 256; ++k){
    int li = k * 256 + tid;
    int g = g0 + li;
    unsigned int v = 0xFFFFFFFFu;
    if (g < 4 * NEDGE){
      int t = g / NEDGE;
      int e = g - t * NEDGE;
      int dst = ei[t * 2 * NEDGE + NEDGE + e];
      bool keep = (t >= 2) || (flag[dst] != 0);   // claim-dst edges only matter if claim used
      if (keep){
        v = (unsigned int)(dst + toff[t]);
        atomicAdd(&hcnt[v >> BSH], 1);
      }
    }
    ldst[li] = v;
  }
  __syncthreads();
  for (int b = tid; b < NBKT; b += 256){
    int c = hcnt[b];
    hpos[b] = c ? atomicAdd(&cursor[b], c) : 0;
  }
  __syncthreads();
  #pragma unroll 4
  for (int k = 0; k < B3_CHUNK / 256; ++k){
    int li = k * 256 + tid;
    int g = g0 + li;
    unsigned int v = ldst[li];
    if (v != 0xFFFFFFFFu){
      int t = g / NEDGE;
      int e = g - t * NEDGE;
      int src = ei[t * 2 * NEDGE + e];
      int off = atomicAdd(&hpos[v >> BSH], 1);
      pairs[off] = ((v & ((1u << BSH) - 1)) << 18) | (unsigned int)src;
    }
  }
}

__global__ void k_bscan(const int* __restrict__ cursor, int* __restrict__ colBase,
                        int* __restrict__ R){
  __shared__ int s[1024];
  int tid = threadIdx.x;
  int c = (tid < NBKT) ? (cursor[tid] - tid * CAP) : 0;
  s[tid] = c;
  __syncthreads();
  for (int off = 1; off < 1024; off <<= 1){
    int t = (tid >= off) ? s[tid - off] : 0;
    __syncthreads();
    s[tid] += t;
    __syncthreads();
  }
  if (tid < NBKT) colBase[tid] = s[tid] - c;
  if (tid == 1023) R[NT] = s[1023];
}

__global__ __launch_bounds__(256) void k_csr(const unsigned int* __restrict__ pairs,
                                             const int* __restrict__ cursor,
                                             const int* __restrict__ colBase,
                                             int* __restrict__ R, int* __restrict__ col){
  __shared__ int h[1024];
  __shared__ int aux[256];
  int b = blockIdx.x, tid = threadIdx.x;
  int cnt   = cursor[b] - b * CAP;
  int base  = colBase[b];
  int pbase = b * CAP;
  for (int j = tid; j < 1024; j += 256) h[j] = 0;
  __syncthreads();
  for (int i = tid; i < cnt; i += 256)
    atomicAdd(&h[pairs[pbase + i] >> 18], 1);
  __syncthreads();
  int j4 = tid * 4;
  int a0 = h[j4], a1 = h[j4+1], a2 = h[j4+2], a3 = h[j4+3];
  int tsum = a0 + a1 + a2 + a3;
  aux[tid] = tsum;
  __syncthreads();
  for (int off = 1; off < 256; off <<= 1){
    int t = (tid >= off) ? aux[tid - off] : 0;
    __syncthreads();
    aux[tid] += t;
    __syncthreads();
  }
  int ex = aux[tid] - tsum;
  h[j4]   = ex;
  h[j4+1] = ex + a0;
  h[j4+2] = ex + a0 + a1;
  h[j4+3] = ex + a0 + a1 + a2;
  int nodeBase = b << BSH;
  #pragma unroll
  for (int k = 0; k < 4; k++){
    int n = nodeBase + j4 + k;
    if (n < NT) R[n] = base + h[j4 + k];
  }
  __syncthreads();
  for (int i = tid; i < cnt; i += 256){
    unsigned int p = pairs[pbase + i];
    int r = atomicAdd(&h[p >> 18], 1);
    col[base + r] = (int)(p & 0x3FFFFu);
  }
}

// ---- mean aggregation: 4 dst rows per wave, 16 lanes x 8B per row, no cross-row reduce ----
__global__ __launch_bounds__(256) void k_agg(const unsigned short* __restrict__ X0,
                                             const unsigned short* __restrict__ X1,
                                             const int* __restrict__ R,
                                             const int* __restrict__ col,
                                             unsigned short* __restrict__ M0,
                                             unsigned short* __restrict__ M1,
                                             const int* __restrict__ list,
                                             const int* __restrict__ nu_ptr,
                                             int RbA, int RbB, int nd0_param, int njobs_param){
  int tid  = threadIdx.x;
  int lane = tid & 63;
  int g    = lane >> 4;          // row group 0..3
  int fl   = lane & 15;          // feature slot: features [4fl, 4fl+4)
  int wv   = (int)blockIdx.x * 4 + (tid >> 6);
  int nu     = list ? *nu_ptr : 0;
  int njobs  = list ? 2 * nu : njobs_param;
  int nd0    = list ? nu : nd0_param;
  int j = wv * 4 + g;
  bool active = j < njobs;
  int sub_t = 0, idx = 0, row = 0, node = 0;
  if (active){
    sub_t = (j >= nd0) ? 1 : 0;
    idx = j - (sub_t ? nd0 : 0);
    row = list ? list[idx] : idx;
    node = (sub_t ? RbB : RbA) + row;
  }
  const unsigned short* X = sub_t ? X1 : X0;
  unsigned short* Mo = sub_t ? M1 : M0;
  int rbeg = 0, rend = 0;
  if (active){ rbeg = R[node]; rend = R[node + 1]; }
  int deg = rend - rbeg;
  float4 acc = {0.f, 0.f, 0.f, 0.f};
  for (int p = rbeg; p < rend; p += 8){
    int nb = rend - p; if (nb > 8) nb = 8;
    int cid = 0;
    if (fl < nb) cid = col[p + fl];      // 1 coalesced id prefetch per 8 edges
    #pragma unroll
    for (int k = 0; k < 8; ++k){
      int c = __shfl(cid, (g << 4) + k, 64);
      if (k < nb){
        uint2 d = *(const uint2*)(X + c * F + fl * 4);
        acc.x += __uint_as_float(d.x << 16);
        acc.y += __uint_as_float(d.x & 0xffff0000u);
        acc.z += __uint_as_float(d.y << 16);
        acc.w += __uint_as_float(d.y & 0xffff0000u);
      }
    }
  }
  if (active){
    float r = deg ? (1.0f / (float)deg) : 0.f;
    ushort4 o;
    o.x = f2b(acc.x * r); o.y = f2b(acc.y * r);
    o.z = f2b(acc.z * r); o.w = f2b(acc.w * r);
    *(ushort4*)(Mo + (long long)idx * F + fl * 4) = o;
  }
}

// ---- fused multi-source GEMM: H = act(sum_j Aj@Wj + bias) ----
typedef __bf16 bf16x8 __attribute__((ext_vector_type(8)));
typedef float  f32x4  __attribute__((ext_vector_type(4)));
#define WT_STRIDE 72

__global__ __launch_bounds__(256) void k_gemm(
    const unsigned short* __restrict__ A0, const unsigned short* __restrict__ A1,
    const unsigned short* __restrict__ A2, const unsigned short* __restrict__ A3,
    const float* __restrict__ W0, const float* __restrict__ W1,
    const float* __restrict__ W2, const float* __restrict__ W3,
    const float* __restrict__ b0, const float* __restrict__ b1,
    unsigned short* __restrict__ Hout,
    const int* __restrict__ Alist, int amask,
    const int* __restrict__ Mptr, int Mparam, int ns, int relu)
{
  int M = Mptr ? *Mptr : Mparam;
  if ((int)blockIdx.x * 64 >= M) return;     // block-uniform early exit
  __shared__ __align__(16) unsigned short WT[4 * 64 * WT_STRIDE];
  const float* Ws[4] = {W0, W1, W2, W3};
  const unsigned short* As[4] = {A0, A1, A2, A3};
  int tid = threadIdx.x;
  for (int j = 0; j < ns; j++){
    const float* Wj = Ws[j];
    #pragma unroll
    for (int q = 0; q < 16; q++){
      int idx = q * 256 + tid;
      int k = idx >> 6, n = idx & 63;
      WT[j * 64 * WT_STRIDE + n * WT_STRIDE + k] = f2b(Wj[idx]);
    }
  }
  __syncthreads();
  int wave = tid >> 6, lane = tid & 63;
  int quad = lane >> 4, l16 = lane & 15;
  int m0 = blockIdx.x * 64 + wave * 16;
  int arow = m0 + l16; if (arow >= M) arow = M - 1;
  int arows[4];
  #pragma unroll
  for (int j = 0; j < 4; j++)
    arows[j] = ((amask >> j) & 1) ? Alist[arow] : arow;
  f32x4 z = {0.f, 0.f, 0.f, 0.f};
  f32x4 acc[4] = {z, z, z, z};
  for (int j = 0; j < ns; j++){
    const unsigned short* Aj = As[j];
    #pragma unroll
    for (int kk = 0; kk < 64; kk += 32){
      bf16x8 af = *(const bf16x8*)(Aj + (long long)arows[j] * F + kk + quad * 8);
      #pragma unroll
      for (int c = 0; c < 4; c++){
        const unsigned short* bp = &WT[j * 64 * WT_STRIDE + (c * 16 + l16) * WT_STRIDE + kk + quad * 8];
        bf16x8 bfr = *(const bf16x8*)bp;
        acc[c] = __builtin_amdgcn_mfma_f32_16x16x32_bf16(af, bfr, acc[c], 0, 0, 0);
      }
    }
  }
  #pragma unroll
  for (int c = 0; c < 4; c++){
    int n = c * 16 + l16;
    float bv = b0[n] + (b1 ? b1[n] : 0.f);
    #pragma unroll
    for (int r = 0; r < 4; r++){
      int row = m0 + quad * 4 + r;
      if (row < M){
        float v = acc[c][r] + bv;
        if (relu) v = fmaxf(v, 0.f);
        Hout[(long long)row * F + n] = f2b(v);
      }
    }
  }
}

// ---------------- final classifier: wave per batch row; fp32 out ----------------
__global__ void k_out(const unsigned short* __restrict__ h2,
                      const int* __restrict__ cbi,
                      const int* __restrict__ rank,
                      const float* __restrict__ Wc,
                      const float* __restrict__ bcp,
                      float* __restrict__ out){
  int w = (int)(((unsigned)blockIdx.x * blockDim.x + threadIdx.x) >> 6);
  int lane = threadIdx.x & 63;
  if (w >= BATCH) return;
  int rk = rank[cbi[w]];
  float v = b2f(h2[(long long)rk * F + lane]);
  float p0 = v * Wc[lane * 2];
  float p1 = v * Wc[lane * 2 + 1];
  for (int off = 32; off; off >>= 1){
    p0 += __shfl_xor(p0, off, 64);
    p1 += __shfl_xor(p1, off, 64);
  }
  if (lane == 0){
    out[2 * w]     = p0 + bcp[0];
    out[2 * w + 1] = p1 + bcp[1];
  }
}

extern "C" void kernel_launch(void* const* d_in, const int* in_sizes, int n_in,
                              void* d_out, int out_size, void* d_ws, size_t ws_size,
                              hipStream_t stream)
{
  const float* x_c = (const float*)d_in[0];
  const float* x_e = (const float*)d_in[1];
  const float* x_v = (const float*)d_in[2];
  const int*   ei  = (const int*)d_in[3];
  const int*   cbi = (const int*)d_in[4];
  const float* Wl1 = (const float*)d_in[5];
  const float* bl1 = (const float*)d_in[6];
  const float* Wr1 = (const float*)d_in[7];
  const float* Wl2 = (const float*)d_in[8];
  const float* bl2 = (const float*)d_in[9];
  const float* Wr2 = (const float*)d_in[10];
  const float* Wc  = (const float*)d_in[11];
  const float* bc  = (const float*)d_in[12];
  float* out = (float*)d_out;

  char* ws = (char*)d_ws;
  size_t off = 0;
  auto alloc = [&](size_t bytes) -> char* {
    char* p = ws + off;
    off += (bytes + 255) & ~(size_t)255;
    return p;
  };
  int* R       = (int*)alloc((size_t)(NT + 1) * 4);
  int* cursor  = (int*)alloc((size_t)NBKT * 4);
  int* colBase = (int*)alloc((size_t)NBKT * 4);
  int* flag    = (int*)alloc((size_t)N_CLAIM * 4);
  int* rank    = (int*)alloc((size_t)N_CLAIM * 4);
  int* list    = (int*)alloc((size_t)BATCH * 4);
  int* nu      = (int*)alloc(256);
  int* col     = (int*)alloc((size_t)4 * NEDGE * 4);
  unsigned int* pairs = (unsigned int*)alloc((size_t)NBKT * CAP * 4);   // dead after k_csr
  unsigned short* xb_c  = (unsigned short*)alloc((size_t)N_CLAIM    * F * 2);
  unsigned short* xb_e  = (unsigned short*)alloc((size_t)N_ENTITY   * F * 2);
  unsigned short* xb_v  = (unsigned short*)alloc((size_t)N_EVIDENCE * F * 2);
  unsigned short* mean0 = (unsigned short*)alloc((size_t)BATCH * F * 2);   // compacted
  unsigned short* mean1 = (unsigned short*)alloc((size_t)BATCH * F * 2);   // compacted
  unsigned short* h1c   = (unsigned short*)alloc((size_t)BATCH * F * 2);   // compacted
  unsigned short* h1e   = (unsigned short*)alloc((size_t)N_ENTITY   * F * 2);
  unsigned short* h1v   = (unsigned short*)alloc((size_t)N_EVIDENCE * F * 2);
  unsigned short* mean2 = (unsigned short*)pairs;   // alias dead pairs region
  unsigned short* mean3 = (unsigned short*)((char*)pairs + (size_t)N_ENTITY * F * 2);
  unsigned short* h2c   = mean2;                    // compacted; mean2 dead after entity GEMM

  hipMemsetAsync(flag, 0, (size_t)N_CLAIM * 4, stream);
  hipMemsetAsync(nu, 0, 4, stream);

  k_mark<<<(BATCH + 255) / 256, 256, 0, stream>>>(cbi, flag);
  k_rank<<<(N_CLAIM + 255) / 256, 256, 0, stream>>>(flag, rank, list, nu);
  k_cast<<<(N_CLAIM    * F / 4 + 255) / 256, 256, 0, stream>>>(x_c, xb_c, N_CLAIM    * F / 4);
  k_cast<<<(N_ENTITY   * F / 4 + 255) / 256, 256, 0, stream>>>(x_e, xb_e, N_ENTITY   * F / 4);
  k_cast<<<(N_EVIDENCE * F / 4 + 255) / 256, 256, 0, stream>>>(x_v, xb_v, N_EVIDENCE * F / 4);

  k_init<<<(NBKT + 255) / 256, 256, 0, stream>>>(cursor);
  k_bscatter<<<B3_BLOCKS, 256, 0, stream>>>(ei, flag, cursor, pairs);
  k_bscan<<<1, 1024, 0, stream>>>(cursor, colBase, R);
  k_csr<<<NBKT, 256, 0, stream>>>(pairs, cursor, colBase, R, col);

  // ---- layer 1 aggregation ----
  k_agg<<<(2 * BATCH + 15) / 16, 256, 0, stream>>>(
      xb_e, xb_v, R, col, mean0, mean1, list, nu, 0, N_CLAIM, 0, 0);
  k_agg<<<(N_ENTITY + N_EVIDENCE + 15) / 16, 256, 0, stream>>>(
      xb_c, xb_c, R, col, mean2, mean3, nullptr, nullptr,
      2 * N_CLAIM, 2 * N_CLAIM + N_ENTITY, N_ENTITY, N_ENTITY + N_EVIDENCE);

  // ---- layer 1 transforms ----
  k_gemm<<<(BATCH + 63) / 64, 256, 0, stream>>>(mean0, mean1, xb_c, xb_c,
        Wl1, Wl1 + 4096, Wr1, Wr1 + 4096, bl1, bl1 + 64, h1c,
        list, 0b1100, nu, 0, 4, 1);
  k_gemm<<<(N_ENTITY + 63) / 64, 256, 0, stream>>>(mean2, xb_e, nullptr, nullptr,
        Wl1 + 2 * 4096, Wr1 + 2 * 4096, nullptr, nullptr, bl1 + 128, nullptr, h1e,
        nullptr, 0, nullptr, N_ENTITY, 2, 1);
  k_gemm<<<(N_EVIDENCE + 63) / 64, 256, 0, stream>>>(mean3, xb_v, nullptr, nullptr,
        Wl1 + 3 * 4096, Wr1 + 3 * 4096, nullptr, nullptr, bl1 + 192, nullptr, h1v,
        nullptr, 0, nullptr, N_EVIDENCE, 2, 1);

  // ---- layer 2: claims only, compacted ----
  k_agg<<<(2 * BATCH + 15) / 16, 256, 0, stream>>>(
      h1e, h1v, R, col, mean0, mean1, list, nu, 0, N_CLAIM, 0, 0);
  k_gemm<<<(BATCH + 63) / 64, 256, 0, stream>>>(mean0, mean1, h1c, h1c,
        Wl2, Wl2 + 4096, Wr2, Wr2 + 4096, bl2, bl2 + 64, h2c,
        nullptr, 0, nu, 0, 4, 0);

  // ---- classifier ----
  k_out<<<(BATCH * 64 + 255) / 256, 256, 0, stream>>>(h2c, cbi, rank, Wc, bc, out);
}